// Round 13
// baseline (175.919 us; speedup 1.0000x reference)
//
#include <hip/hip_runtime.h>
#include <hip/hip_bf16.h>

// DCNv2 inception, R13: tile-local param repack + LDS param staging.
// Arithmetic from R12: per wave-tap wall ~10.9k cycles vs ~900 VALU-issue;
// extra waves (R10) don't reduce the stall -> shared saturating resource
// invisible to our counters. Suspect: address translation on param loads
// (each tap touches 3 fresh 4KB pages, 32KB stride, 16MB once-read region;
// page walker is per-XCD shared -> batch prefetch queues, more waves worsen).
// Fix: prep phase-3 repacks params tile-locally (parmT[tile][g][dy16|dx16|
// mk16], coalesced page-sequential); k_dcn bulk-stages its 15.9KB into LDS
// once, per-tap params become 3x ds_read_b32. Window/WS=68 untouched;
// LDS 65,280+15,936 = 81,216 <= 81,920 -> still 2 blocks/CU.

typedef __attribute__((ext_vector_type(8))) short bf16x8;
typedef __attribute__((ext_vector_type(8))) unsigned short u16x8;
typedef __attribute__((ext_vector_type(4))) float f32x4;
typedef __attribute__((ext_vector_type(2))) float f32x2;

#define WR 16    // window rows
#define WC 30    // window cols
#define WS 68    // window position stride in shorts (34 dwords -> +2 bank rotate)
#define SLS 20   // slab o-stride in floats
#define PARM_OFF 65280   // byte offset of param block in smem

__device__ __forceinline__ unsigned short f2bf(float f) {
    __hip_bfloat16 h = __float2bfloat16(f);
    return *reinterpret_cast<unsigned short*>(&h);
}
__device__ __forceinline__ f32x2 unpk(unsigned u) {
    f32x2 r;
    r[0] = __uint_as_float(u << 16);
    r[1] = __uint_as_float(u & 0xffff0000u);
    return r;
}

// Merged prep:
//  [0,256):      x[b][c][h][w] f32 -> xTb[b][h][w][c] bf16
//  [256,1584):   f[o][c][k] f32 -> wpF fragment-major
//  [1584,17520): params -> parmT[tile][g][sel][16]  (g: br0 0-8|br1 9-33|br2 34-82)
__global__ __launch_bounds__(256) void k_prep(
    const float* __restrict__ x,
    const float* __restrict__ f1, const float* __restrict__ f2, const float* __restrict__ f3,
    const float* __restrict__ off1, const float* __restrict__ msk1,
    const float* __restrict__ off2, const float* __restrict__ msk2,
    const float* __restrict__ off3, const float* __restrict__ msk3,
    unsigned short* __restrict__ xTb,
    unsigned short* __restrict__ wp1, unsigned short* __restrict__ wp2, unsigned short* __restrict__ wp3,
    float* __restrict__ parmT) {
    __shared__ float tile[64][65];
    int bid = blockIdx.x;
    int tid = threadIdx.x;
    if (bid < 256) {
        int b = bid >> 6, h = bid & 63;
        {
            int w = tid & 63, c4 = tid >> 6;
            const float* xp = x + (((b * 64) * 64 + h) * 64) + w;
            #pragma unroll
            for (int i = 0; i < 16; ++i) {
                int c = c4 * 16 + i;
                tile[c][w] = xp[c * 4096];
            }
        }
        __syncthreads();
        {
            int c = tid & 63, w4 = tid >> 6;
            unsigned short* op = xTb + (((b * 64 + h) * 64) * 64) + c;
            #pragma unroll
            for (int i = 0; i < 16; ++i) {
                int ww = w4 * 16 + i;
                op[ww * 64] = f2bf(tile[c][ww]);
            }
        }
    } else if (bid < 1584) {
        int idx = (bid - 256) * 256 + tid;      // 83*4096 = 339968 total
        const float* f; unsigned short* wp; int K, rel;
        if (idx < 36864)       { f = f1; wp = wp1; K = 9;  rel = idx; }
        else if (idx < 139264) { f = f2; wp = wp2; K = 25; rel = idx - 36864; }
        else                   { f = f3; wp = wp3; K = 49; rel = idx - 139264; }
        int k    = rel >> 12;
        int r2   = rel & 4095;
        int ct   = r2 >> 10;
        int cg   = (r2 >> 9) & 1;
        int lane = (r2 >> 3) & 63;
        int j    = r2 & 7;
        int o = ct * 16 + (lane & 15);
        int c = cg * 32 + (lane >> 4) * 8 + j;
        wp[rel] = f2bf(f[(o * 64 + c) * K + k]);
    } else {
        int e = (bid - 1584) * 256 + tid;       // 1024*3984 = 4,079,616 exact
        int t = e / 3984;
        int r = e - t * 3984;
        int g = r / 48;
        int j = r - g * 48;
        int sel = j >> 4;                       // 0=dy,1=dx,2=mk
        int l = j & 15;
        int b = t >> 8, h = (t >> 2) & 63, w0 = (t & 3) << 4;
        const float* src;
        if (g < 9)       { int k = g;      src = (sel == 2) ? msk1 + (b * 9  + k) * 4096 : off1 + (((b * 9  + k) << 1) + sel) * 4096; }
        else if (g < 34) { int k = g - 9;  src = (sel == 2) ? msk2 + (b * 25 + k) * 4096 : off2 + (((b * 25 + k) << 1) + sel) * 4096; }
        else             { int k = g - 34; src = (sel == 2) ? msk3 + (b * 49 + k) * 4096 : off3 + (((b * 49 + k) << 1) + sel) * 4096; }
        parmT[e] = src[(h << 6) + w0 + l];
    }
}

__global__ __launch_bounds__(512, 4) void k_dcn(
    const unsigned short* __restrict__ xTb,
    const unsigned short* __restrict__ wp1, const unsigned short* __restrict__ wp2,
    const unsigned short* __restrict__ wp3, const float* __restrict__ parmT,
    float* __restrict__ out) {

    __shared__ __align__(16) unsigned char smem[PARM_OFF + 83 * 48 * 4];  // 81,216 B
    unsigned short* win = (unsigned short*)smem;
    float* slab = (float*)smem;          // aliased over window after taps done

    int tile = blockIdx.x;               // 0..1023
    int b  = tile >> 8;
    int h  = (tile >> 2) & 63;
    int w0 = (tile & 3) << 4;

    int tid  = threadIdx.x;
    int wv   = tid >> 6;                 // 0..7
    int lane = tid & 63;
    int quad = lane >> 4;
    int l16  = lane & 15;
    int ylo  = h - 7, cxlo = w0 - 7;

    const unsigned short* xb = xTb + ((size_t)b << 18);

    // ---- stage window: 480 positions x 128 B, coalesced ----
    {
        int j = tid & 7;
        for (int p = tid >> 3; p < WR * WC; p += 64) {
            int r = p / WC, cc = p - r * WC;
            int y = min(max(ylo + r, 0), 63);
            int x = min(max(cxlo + cc, 0), 63);
            *(u16x8*)(win + p * WS + j * 8) =
                *(const u16x8*)(xb + (((y << 6) + x) << 6) + j * 8);
        }
    }
    // ---- stage params: 15,936 B coalesced from tile-local repack ----
    {
        const f32x4* psrc = (const f32x4*)(parmT + (size_t)tile * 3984);
        f32x4* pdst = (f32x4*)(smem + PARM_OFF);
        for (int i = tid; i < 996; i += 512) pdst[i] = psrc[i];
    }
    __syncthreads();

    int pw   = w0 + l16;
    int ch0  = quad << 3;
    int lofs = lane << 3;                // lane*8 shorts = lane*16 B

    // ---- per-wave descriptor: branch + tap range + global param index ----
    const unsigned short* wpF;
    int ks, ke, kw, pad, gbase;
    switch (wv) {
        case 0:  wpF = wp1; kw = 3; pad = 1; ks = 0;  ke = 9;  gbase = 0;  break;
        case 1:  wpF = wp2; kw = 5; pad = 2; ks = 0;  ke = 12; gbase = 9;  break;
        case 2:  wpF = wp2; kw = 5; pad = 2; ks = 12; ke = 25; gbase = 21; break;
        case 3:  wpF = wp3; kw = 7; pad = 3; ks = 0;  ke = 10; gbase = 34; break;
        case 4:  wpF = wp3; kw = 7; pad = 3; ks = 10; ke = 20; gbase = 44; break;
        case 5:  wpF = wp3; kw = 7; pad = 3; ks = 20; ke = 30; gbase = 54; break;
        case 6:  wpF = wp3; kw = 7; pad = 3; ks = 30; ke = 40; gbase = 64; break;
        default: wpF = wp3; kw = 7; pad = 3; ks = 40; ke = 49; gbase = 74; break;
    }
    const float* plw = (const float*)(smem + PARM_OFF) + (gbase - ks) * 48;

    f32x4 acc[4];
    #pragma unroll
    for (int i = 0; i < 4; ++i) acc[i] = (f32x4){0.f, 0.f, 0.f, 0.f};

    int ky = ks / kw, kx = ks - ky * kw;

    for (int k = ks; k < ke; ++k) {
        const float* pl = plw + k * 48;
        float dy = pl[l16];
        float dx = pl[16 + l16];
        float mk = pl[32 + l16];

        float py = (float)(h - pad + ky) + dy;
        float px = (float)(pw - pad + kx) + dx;
        float y0f = floorf(py), x0f = floorf(px);
        float wy = py - y0f, wx = px - x0f;
        int y0 = (int)y0f, x0 = (int)x0f;
        int y1 = y0 + 1, x1 = x0 + 1;
        float fy0 = ((unsigned)y0 < 64u) ? (1.f - wy) * mk : 0.f;
        float fy1 = ((unsigned)y1 < 64u) ? wy * mk         : 0.f;
        float gx0 = ((unsigned)x0 < 64u) ? (1.f - wx)      : 0.f;
        float gx1 = ((unsigned)x1 < 64u) ? wx              : 0.f;
        float w00 = fy0 * gx0, w01 = fy0 * gx1, w10 = fy1 * gx0, w11 = fy1 * gx1;

        int r0 = y0 - ylo, r1 = r0 + 1;
        int c0 = x0 - cxlo, c1 = c0 + 1;
        bool oow = ((w00 != 0.f) & (((unsigned)r0 >= WR) | ((unsigned)c0 >= WC)))
                 | ((w01 != 0.f) & (((unsigned)r0 >= WR) | ((unsigned)c1 >= WC)))
                 | ((w10 != 0.f) & (((unsigned)r1 >= WR) | ((unsigned)c0 >= WC)))
                 | ((w11 != 0.f) & (((unsigned)r1 >= WR) | ((unsigned)c1 >= WC)));
        int r0c = min(max(r0, 0), WR - 1), r1c = min(max(r1, 0), WR - 1);
        int c0c = min(max(c0, 0), WC - 1), c1c = min(max(c1, 0), WC - 1);
        int p00 = (r0c * WC + c0c) * WS;
        int p01 = (r0c * WC + c1c) * WS;
        int p10 = (r1c * WC + c0c) * WS;
        int p11 = (r1c * WC + c1c) * WS;

        union U { u16x8 v; unsigned u[4]; };
        U g00a, g01a, g10a, g11a, g00b, g01b, g10b, g11b;
        g00a.v = *(const u16x8*)(win + p00 + ch0);
        g01a.v = *(const u16x8*)(win + p01 + ch0);
        g10a.v = *(const u16x8*)(win + p10 + ch0);
        g11a.v = *(const u16x8*)(win + p11 + ch0);
        g00b.v = *(const u16x8*)(win + p00 + 32 + ch0);
        g01b.v = *(const u16x8*)(win + p01 + 32 + ch0);
        g10b.v = *(const u16x8*)(win + p10 + 32 + ch0);
        g11b.v = *(const u16x8*)(win + p11 + 32 + ch0);

        if (oow) {   // valid corner outside window: needs |off|>~4sd, ~never
            int y0g = min(max(y0, 0), 63), y1g = min(max(y1, 0), 63);
            int x0g = min(max(x0, 0), 63), x1g = min(max(x1, 0), 63);
            int o00 = ((y0g << 6) + x0g) << 6;
            int o01 = ((y0g << 6) + x1g) << 6;
            int o10 = ((y1g << 6) + x0g) << 6;
            int o11 = ((y1g << 6) + x1g) << 6;
            g00a.v = *(const u16x8*)(xb + o00 + ch0);
            g01a.v = *(const u16x8*)(xb + o01 + ch0);
            g10a.v = *(const u16x8*)(xb + o10 + ch0);
            g11a.v = *(const u16x8*)(xb + o11 + ch0);
            g00b.v = *(const u16x8*)(xb + o00 + 32 + ch0);
            g01b.v = *(const u16x8*)(xb + o01 + 32 + ch0);
            g10b.v = *(const u16x8*)(xb + o10 + 32 + ch0);
            g11b.v = *(const u16x8*)(xb + o11 + 32 + ch0);
        }

        f32x2 W00 = {w00, w00}, W01 = {w01, w01}, W10 = {w10, w10}, W11 = {w11, w11};
        union { bf16x8 v; unsigned short u[8]; } A0, A1;
        #pragma unroll
        for (int j2 = 0; j2 < 4; ++j2) {
            f32x2 s0 = W00 * unpk(g00a.u[j2]) + W01 * unpk(g01a.u[j2])
                     + W10 * unpk(g10a.u[j2]) + W11 * unpk(g11a.u[j2]);
            f32x2 s1 = W00 * unpk(g00b.u[j2]) + W01 * unpk(g01b.u[j2])
                     + W10 * unpk(g10b.u[j2]) + W11 * unpk(g11b.u[j2]);
            A0.u[2 * j2]     = f2bf(s0[0]);
            A0.u[2 * j2 + 1] = f2bf(s0[1]);
            A1.u[2 * j2]     = f2bf(s1[0]);
            A1.u[2 * j2 + 1] = f2bf(s1[1]);
        }

        const unsigned short* wpk = wpF + (k << 12) + lofs;
        #pragma unroll
        for (int ct = 0; ct < 4; ++ct) {
            bf16x8 b0 = *(const bf16x8*)(wpk + ct * 1024);
            bf16x8 b1 = *(const bf16x8*)(wpk + ct * 1024 + 512);
            acc[ct] = __builtin_amdgcn_mfma_f32_16x16x32_bf16(A0.v, b0, acc[ct], 0, 0, 0);
            acc[ct] = __builtin_amdgcn_mfma_f32_16x16x32_bf16(A1.v, b1, acc[ct], 0, 0, 0);
        }

        if (++kx == kw) { kx = 0; ++ky; }
    }

    __syncthreads();    // all waves done reading window; safe to alias as slab

    #pragma unroll
    for (int ct = 0; ct < 4; ++ct) {
        *(f32x4*)&slab[wv * 1280 + (ct * 16 + l16) * SLS + quad * 4] = acc[ct];
    }
    __syncthreads();

    // in-block reduce + store: 768 items = 192 o x 4 groups of 4 px
    // br0 (o<64): slab 0; br1: slabs 1+2; br2: slabs 3..7
    for (int it = tid; it < 768; it += 512) {
        int g = it & 3;
        int o = it >> 2;            // 0..191 (concat order br0|br1|br2)
        int oo = o & 63;
        int base = oo * SLS + g * 4;
        f32x4 v;
        if (o < 64) {
            v = *(const f32x4*)&slab[base];
        } else if (o < 128) {
            f32x4 a0 = *(const f32x4*)&slab[1 * 1280 + base];
            f32x4 a1 = *(const f32x4*)&slab[2 * 1280 + base];
            #pragma unroll
            for (int r = 0; r < 4; ++r) v[r] = a0[r] + a1[r];
        } else {
            f32x4 a0 = *(const f32x4*)&slab[3 * 1280 + base];
            f32x4 a1 = *(const f32x4*)&slab[4 * 1280 + base];
            f32x4 a2 = *(const f32x4*)&slab[5 * 1280 + base];
            f32x4 a3 = *(const f32x4*)&slab[6 * 1280 + base];
            f32x4 a4 = *(const f32x4*)&slab[7 * 1280 + base];
            #pragma unroll
            for (int r = 0; r < 4; ++r) v[r] = (a0[r] + a1[r]) + (a2[r] + a3[r]) + a4[r];
        }
        *(f32x4*)&out[(((size_t)b * 192 + o) * 64 + h) * 64 + w0 + g * 4] = v;
    }
}

extern "C" void kernel_launch(void* const* d_in, const int* in_sizes, int n_in,
                              void* d_out, int out_size, void* d_ws, size_t ws_size,
                              hipStream_t stream) {
    const float* x    = (const float*)d_in[0];
    const float* f1   = (const float*)d_in[1];
    const float* off1 = (const float*)d_in[2];
    const float* msk1 = (const float*)d_in[3];
    const float* f2   = (const float*)d_in[4];
    const float* off2 = (const float*)d_in[5];
    const float* msk2 = (const float*)d_in[6];
    const float* f3   = (const float*)d_in[7];
    const float* off3 = (const float*)d_in[8];
    const float* msk3 = (const float*)d_in[9];
    float* out = (float*)d_out;

    // ws: xTb 2MB bf16 | wpF1/2/3 bf16 (0.65MB) | parmT f32 (16.3MB)
    unsigned short* xTb = (unsigned short*)d_ws;
    unsigned short* wp1 = xTb + 4 * 64 * 64 * 64;
    unsigned short* wp2 = wp1 + 9 * 4096;
    unsigned short* wp3 = wp2 + 25 * 4096;
    float* parmT = (float*)(wp3 + 49 * 4096);   // 1024*3984 floats

    k_prep<<<dim3(17520), dim3(256), 0, stream>>>(x, f1, f2, f3,
                                                  off1, msk1, off2, msk2, off3, msk3,
                                                  xTb, wp1, wp2, wp3, parmT);
    k_dcn<<<dim3(1024), dim3(512), 0, stream>>>(xTb, wp1, wp2, wp3, parmT, out);
}